// Round 25
// baseline (289.278 us; speedup 1.0000x reference)
//
#include <hip/hip_runtime.h>

#define N_SRC 100000
#define N_DST 20000
#define NE 640000
#define IN_F 256
#define NH 4
#define DF 32
#define NCOL 128  /* NH*DF */
#define NTILES ((N_SRC + 63) / 64)  /* 1563 */

// ---------------- K0: fold attn vectors into W (fp64) + zero cnt ----------
__global__ void k_prep(const float* __restrict__ W,
                       const float* __restrict__ attn_l,
                       const float* __restrict__ attn_r,
                       double* __restrict__ Wlr_t,
                       int* __restrict__ cnt) {
    int k = threadIdx.x;  // 256 threads
    for (int j = 0; j < 8; ++j) {
        const float* attn = (j < 4) ? attn_l : attn_r;
        int hh = j & 3;
        double s = 0.0;
        for (int d = 0; d < DF; ++d)
            s += (double)W[k * NCOL + hh * DF + d] * (double)attn[hh * DF + d];
        Wlr_t[(size_t)j * IN_F + k] = s;
    }
    for (int i = k; i < N_DST; i += 256) cnt[i] = 0;
}

// ---------------- K1: persistent W-in-LDS GEMM + el + histogram ------------
// 1 block/CU (153 KB LDS): W staged ONCE into wg[256][128]; inner-loop W
// reads are wave-uniform ds_read_b128 broadcasts (lgkm, deterministic) —
// replaces r22's s_load path whose 32 KB/block chunk thrashed the scalar L1
// across 4 phase-shifted blocks (the VALUBusy-48% stall). Tiles grid-strided.
// FMA expression and k-order verbatim from r22 -> h bit-identical; wlds
// values/order identical -> el bit-identical.
__global__ __launch_bounds__(512) void k_gemm(const float* __restrict__ x,
                                              const float* __restrict__ W,
                                              const double* __restrict__ Wlr_t,
                                              const int* __restrict__ dst_idx,
                                              float* __restrict__ h,
                                              double* __restrict__ el,
                                              int* __restrict__ cnt,
                                              int* __restrict__ rank) {
    __shared__ float wg[256][128];   // 128 KB (uniform reads -> no conflicts)
    __shared__ float xs[64][68];     // 17.4 KB
    __shared__ double wlds[4][258];  // 8.25 KB (full el rows)
    const int tid = threadIdx.x;
    const int lane = tid & 63;
    const int cg = __builtin_amdgcn_readfirstlane(tid >> 6);  // 0..7
    const int c0 = cg * 16;
    const int srow = tid >> 3;        // score: row 0..63
    const int shh = tid & 3;          // score: head
    const int shalf = (tid >> 2) & 1; // score: k-half of each chunk

    const int r_a = tid >> 4;        // 0..31
    const int r_b = 32 + (tid >> 4); // 32..63
    const int q4 = (tid & 15) * 4;

    // ---- one-time staging: W (8192 float4) + Wlr el-rows (1024 dbl) ----
    for (int i = tid; i < 256 * 32; i += 512) {
        int kk = i >> 5, q = i & 31;
        *((float4*)&wg[kk][q * 4]) = *((const float4*)(W + (size_t)kk * NCOL + q * 4));
    }
    for (int i = tid; i < 4 * IN_F; i += 512)
        wlds[i >> 8][i & 255] = Wlr_t[(size_t)(i >> 8) * IN_F + (i & 255)];
    __syncthreads();

    for (int tile = blockIdx.x; tile < NTILES; tile += gridDim.x) {
        const int row0 = tile * 64;

        float4 acc0 = make_float4(0.f, 0.f, 0.f, 0.f);
        float4 acc1 = make_float4(0.f, 0.f, 0.f, 0.f);
        float4 acc2 = make_float4(0.f, 0.f, 0.f, 0.f);
        float4 acc3 = make_float4(0.f, 0.f, 0.f, 0.f);
        double sacc = 0.0;

        // prefetch chunk 0 of this tile
        float4 pf0 = make_float4(0.f, 0.f, 0.f, 0.f);
        float4 pf1 = make_float4(0.f, 0.f, 0.f, 0.f);
        if (row0 + r_a < N_SRC)
            pf0 = *((const float4*)(x + (size_t)(row0 + r_a) * IN_F + q4));
        if (row0 + r_b < N_SRC)
            pf1 = *((const float4*)(x + (size_t)(row0 + r_b) * IN_F + q4));

        for (int chunk = 0; chunk < 4; ++chunk) {
            const int kbase = chunk * 64;
            __syncthreads();  // previous xs readers done (incl. prior tile)
            *((float4*)&xs[r_a][q4]) = pf0;
            *((float4*)&xs[r_b][q4]) = pf1;
            __syncthreads();

            if (chunk < 3) {  // prefetch next chunk under this chunk's compute
                const int nk = kbase + 64;
                if (row0 + r_a < N_SRC)
                    pf0 = *((const float4*)(x + (size_t)(row0 + r_a) * IN_F + nk + q4));
                if (row0 + r_b < N_SRC)
                    pf1 = *((const float4*)(x + (size_t)(row0 + r_b) * IN_F + nk + q4));
            }

            // ---- GEMM inner: W via wave-uniform LDS broadcast ----
#pragma unroll 1
            for (int kq = 0; kq < 64; kq += 4) {
                const float* wp0 = &wg[kbase + kq + 0][c0];
                const float* wp1 = &wg[kbase + kq + 1][c0];
                const float* wp2 = &wg[kbase + kq + 2][c0];
                const float* wp3 = &wg[kbase + kq + 3][c0];
                float4 r0a = *((const float4*)(wp0 + 0));
                float4 r0b = *((const float4*)(wp0 + 4));
                float4 r0c = *((const float4*)(wp0 + 8));
                float4 r0d = *((const float4*)(wp0 + 12));
                float4 r1a = *((const float4*)(wp1 + 0));
                float4 r1b = *((const float4*)(wp1 + 4));
                float4 r1c = *((const float4*)(wp1 + 8));
                float4 r1d = *((const float4*)(wp1 + 12));
                float4 r2a = *((const float4*)(wp2 + 0));
                float4 r2b = *((const float4*)(wp2 + 4));
                float4 r2c = *((const float4*)(wp2 + 8));
                float4 r2d = *((const float4*)(wp2 + 12));
                float4 r3a = *((const float4*)(wp3 + 0));
                float4 r3b = *((const float4*)(wp3 + 4));
                float4 r3c = *((const float4*)(wp3 + 8));
                float4 r3d = *((const float4*)(wp3 + 12));
                float4 xv = *((const float4*)&xs[lane][kq]);
                acc0.x += xv.x * r0a.x + xv.y * r1a.x + xv.z * r2a.x + xv.w * r3a.x;
                acc0.y += xv.x * r0a.y + xv.y * r1a.y + xv.z * r2a.y + xv.w * r3a.y;
                acc0.z += xv.x * r0a.z + xv.y * r1a.z + xv.z * r2a.z + xv.w * r3a.z;
                acc0.w += xv.x * r0a.w + xv.y * r1a.w + xv.z * r2a.w + xv.w * r3a.w;
                acc1.x += xv.x * r0b.x + xv.y * r1b.x + xv.z * r2b.x + xv.w * r3b.x;
                acc1.y += xv.x * r0b.y + xv.y * r1b.y + xv.z * r2b.y + xv.w * r3b.y;
                acc1.z += xv.x * r0b.z + xv.y * r1b.z + xv.z * r2b.z + xv.w * r3b.z;
                acc1.w += xv.x * r0b.w + xv.y * r1b.w + xv.z * r2b.w + xv.w * r3b.w;
                acc2.x += xv.x * r0c.x + xv.y * r1c.x + xv.z * r2c.x + xv.w * r3c.x;
                acc2.y += xv.x * r0c.y + xv.y * r1c.y + xv.z * r2c.y + xv.w * r3c.y;
                acc2.z += xv.x * r0c.z + xv.y * r1c.z + xv.z * r2c.z + xv.w * r3c.z;
                acc2.w += xv.x * r0c.w + xv.y * r1c.w + xv.z * r2c.w + xv.w * r3c.w;
                acc3.x += xv.x * r0d.x + xv.y * r1d.x + xv.z * r2d.x + xv.w * r3d.x;
                acc3.y += xv.x * r0d.y + xv.y * r1d.y + xv.z * r2d.y + xv.w * r3d.y;
                acc3.z += xv.x * r0d.z + xv.y * r1d.z + xv.z * r2d.z + xv.w * r3d.z;
                acc3.w += xv.x * r0d.w + xv.y * r1d.w + xv.z * r2d.w + xv.w * r3d.w;
            }

            // ---- score inner: half-dot (32 k) for el[srow][shh] ----
            {
                const int kb = shalf * 32;
#pragma unroll 4
                for (int k = 0; k < 32; k += 4) {
                    float4 xv = *((const float4*)&xs[srow][kb + k]);
                    double2 wa = *((const double2*)&wlds[shh][kbase + kb + k]);
                    double2 wb = *((const double2*)&wlds[shh][kbase + kb + k + 2]);
                    sacc += (double)xv.x * wa.x + (double)xv.y * wa.y
                          + (double)xv.z * wb.x + (double)xv.w * wb.y;
                }
            }
        }

        // write h: lane's row, 16 cols at c0
        {
            int row = row0 + lane;
            if (row < N_SRC) {
                float* hp = h + (size_t)row * NCOL + c0;
                *((float4*)(hp + 0)) = acc0;
                *((float4*)(hp + 4)) = acc1;
                *((float4*)(hp + 8)) = acc2;
                *((float4*)(hp + 12)) = acc3;
            }
        }

        // combine el halves (partner tid^4) and write
        sacc += __shfl_xor(sacc, 4);
        {
            int row = row0 + srow;
            if (shalf == 0 && row < N_SRC)
                el[(size_t)row * NH + shh] = sacc;
        }
    }

    // histogram tail with rank capture (cnt zeroed by k_prep)
    for (int e = blockIdx.x * 512 + tid; e < NE; e += gridDim.x * 512)
        rank[e] = atomicAdd(cnt + dst_idx[e], 1);
}

// ---------------- k_scan: exclusive scan of cnt -> offsets ----------------
__global__ __launch_bounds__(1024) void k_scan(const int* __restrict__ cnt,
                                               int* __restrict__ offsets) {
    __shared__ int wsum[16];
    __shared__ int carry;
    int tid = threadIdx.x, lane = tid & 63, w = tid >> 6;
    if (tid == 0) carry = 0;
    __syncthreads();
    for (int base = 0; base < N_DST; base += 1024) {
        int i = base + tid;
        int v = (i < N_DST) ? cnt[i] : 0;
        int s = v;
#pragma unroll
        for (int off = 1; off < 64; off <<= 1) {
            int t = __shfl_up(s, off);
            if (lane >= off) s += t;
        }
        if (lane == 63) wsum[w] = s;
        __syncthreads();
        int wprefix = 0;
        for (int k = 0; k < w; ++k) wprefix += wsum[k];
        int incl = s + wprefix + carry;
        if (i < N_DST) offsets[i + 1] = incl;
        __syncthreads();
        if (tid == 1023) carry = incl;
        __syncthreads();
    }
    if (tid == 0) offsets[0] = 0;
}

// ---------------- k_fill: atomic-free scatter via precomputed rank --------
__global__ __launch_bounds__(256) void k_fill(const int* __restrict__ src_idx,
                                              const int* __restrict__ dst_idx,
                                              const int* __restrict__ offsets,
                                              const int* __restrict__ rank,
                                              int* __restrict__ edge_src) {
    int gid = blockIdx.x * 256 + threadIdx.x;
    if (gid >= NE) return;
    int d = dst_idx[gid];
    edge_src[offsets[d] + rank[gid]] = src_idx[gid];
}

// ---------------- K5: fused er + S + normalize + weighted gather ------------
__global__ __launch_bounds__(256) void k_fused(const int* __restrict__ offsets,
                                               const int* __restrict__ edge_src,
                                               const double* __restrict__ el,
                                               const float* __restrict__ x,
                                               const double* __restrict__ Wlr_t,
                                               const int* __restrict__ dst_to_src,
                                               const float* __restrict__ h,
                                               float* __restrict__ out) {
    __shared__ double att_sh[4][4][68];
    __shared__ int    s_sh[4][64];

    const int w = threadIdx.x >> 6;
    const int lane = threadIdx.x & 63;
    const int d = blockIdx.x * 4 + w;
    if (d >= N_DST) return;
    const int beg = offsets[d];
    const int deg = offsets[d + 1] - beg;

    // phase 0: er for this dst (exact fp64 from x)
    double er4[NH];
    {
        const int srcrow = dst_to_src[d];
        float4 xv = *((const float4*)(x + (size_t)srcrow * IN_F + lane * 4));
        const double xd[4] = {(double)xv.x, (double)xv.y, (double)xv.z, (double)xv.w};
#pragma unroll
        for (int hh = 0; hh < 4; ++hh) {
            const double* wp = Wlr_t + (size_t)(4 + hh) * IN_F + lane * 4;
            er4[hh] = xd[0] * wp[0] + xd[1] * wp[1] + xd[2] * wp[2] + xd[3] * wp[3];
        }
#pragma unroll
        for (int hh = 0; hh < 4; ++hh) {
#pragma unroll
            for (int m = 32; m >= 1; m >>= 1)
                er4[hh] += __shfl_xor(er4[hh], m);
        }
    }
    const double er0 = er4[0], er1 = er4[1], er2 = er4[2], er3 = er4[3];

    // phase 1: S[h] per-lane partials + butterfly; stash first-iter e/s
    double sum0 = 0.0, sum1 = 0.0, sum2 = 0.0, sum3 = 0.0;
    double e0r = 0.0, e1r = 0.0, e2r = 0.0, e3r = 0.0;
    int s_first = 0;
    for (int j = lane; j < deg; j += 64) {
        int s = edge_src[beg + j];
        double2 ela = *((const double2*)(el + (size_t)s * NH));
        double2 elb = *((const double2*)(el + (size_t)s * NH + 2));
        double e0 = ela.x + er0; e0 = (e0 >= 0.0) ? e0 : 0.2 * e0;
        double e1 = ela.y + er1; e1 = (e1 >= 0.0) ? e1 : 0.2 * e1;
        double e2 = elb.x + er2; e2 = (e2 >= 0.0) ? e2 : 0.2 * e2;
        double e3 = elb.y + er3; e3 = (e3 >= 0.0) ? e3 : 0.2 * e3;
        sum0 += e0; sum1 += e1; sum2 += e2; sum3 += e3;
        if (j == lane) { s_first = s; e0r = e0; e1r = e1; e2r = e2; e3r = e3; }
    }
#pragma unroll
    for (int m = 32; m >= 1; m >>= 1) {
        sum0 += __shfl_xor(sum0, m);
        sum1 += __shfl_xor(sum1, m);
        sum2 += __shfl_xor(sum2, m);
        sum3 += __shfl_xor(sum3, m);
    }

    if (lane < deg) {
        s_sh[w][lane] = s_first;
        att_sh[w][0][lane] = e0r / sum0;
        att_sh[w][1][lane] = e1r / sum1;
        att_sh[w][2][lane] = e2r / sum2;
        att_sh[w][3][lane] = e3r / sum3;
    }

    // phase 2: 2 edges in flight; lane = (js, col quad cq)
    const int js = lane >> 5;
    const int cq = lane & 31;
    const int hd = cq >> 3;
    const double Shd = (hd == 0) ? sum0 : (hd == 1) ? sum1 : (hd == 2) ? sum2 : sum3;
    const double erhd = (hd == 0) ? er0 : (hd == 1) ? er1 : (hd == 2) ? er2 : er3;

    double acc0 = 0.0, acc1 = 0.0, acc2 = 0.0, acc3 = 0.0;
    for (int j = js; j < deg; j += 2) {
        int s; double att;
        if (j < 64) {
            s = s_sh[w][j];
            att = att_sh[w][hd][j];
        } else {
            s = edge_src[beg + j];
            double e = el[(size_t)s * NH + hd] + erhd;
            e = (e >= 0.0) ? e : 0.2 * e;
            att = e / Shd;
        }
        float4 hv = *((const float4*)(h + (size_t)s * NCOL + cq * 4));
        acc0 += att * (double)hv.x;
        acc1 += att * (double)hv.y;
        acc2 += att * (double)hv.z;
        acc3 += att * (double)hv.w;
    }
    acc0 += __shfl_xor(acc0, 32);
    acc1 += __shfl_xor(acc1, 32);
    acc2 += __shfl_xor(acc2, 32);
    acc3 += __shfl_xor(acc3, 32);

    if (lane < 32) {
        *((float4*)(out + (size_t)d * NCOL + lane * 4)) =
            make_float4((float)acc0, (float)acc1, (float)acc2, (float)acc3);
    }
}

extern "C" void kernel_launch(void* const* d_in, const int* in_sizes, int n_in,
                              void* d_out, int out_size, void* d_ws, size_t ws_size,
                              hipStream_t stream) {
    const float* x      = (const float*)d_in[0];
    const float* W      = (const float*)d_in[1];
    const float* attn_l = (const float*)d_in[2];
    const float* attn_r = (const float*)d_in[3];
    const int* src_idx  = (const int*)d_in[4];
    const int* dst_idx  = (const int*)d_in[5];
    const int* dst_to_src = (const int*)d_in[6];
    float* out = (float*)d_out;

    char* p = (char*)d_ws;
    double* Wlr_t  = (double*)p;  p += (size_t)8 * IN_F * sizeof(double);     // 16 KB
    double* el     = (double*)p;  p += (size_t)N_SRC * NH * sizeof(double);   // 3.2 MB
    float*  h      = (float*)p;   p += (size_t)N_SRC * NCOL * sizeof(float);  // 51.2 MB
    int*    cnt      = (int*)p;   p += (size_t)N_DST * sizeof(int);
    int*    offsets  = (int*)p;   p += (size_t)(N_DST + 1) * sizeof(int);
    int*    rank     = (int*)p;   p += (size_t)NE * sizeof(int);
    int*    edge_src = (int*)p;   p += (size_t)NE * sizeof(int);

    k_prep<<<1, 256, 0, stream>>>(W, attn_l, attn_r, Wlr_t, cnt);
    k_gemm<<<256, 512, 0, stream>>>(x, W, Wlr_t, dst_idx, h, el, cnt, rank);
    k_scan<<<1, 1024, 0, stream>>>(cnt, offsets);
    k_fill<<<(NE + 255) / 256, 256, 0, stream>>>(src_idx, dst_idx, offsets, rank, edge_src);
    k_fused<<<N_DST / 4, 256, 0, stream>>>(offsets, edge_src, el, x, Wlr_t, dst_to_src, h, out);
}

// Round 26
// 225.608 us; speedup vs baseline: 1.2822x; 1.2822x over previous
//
#include <hip/hip_runtime.h>

#define N_SRC 100000
#define N_DST 20000
#define NE 640000
#define IN_F 256
#define NH 4
#define DF 32
#define NCOL 128  /* NH*DF */

// ---------------- K0: fold attn vectors into W (fp64) + zero cnt ----------
__global__ void k_prep(const float* __restrict__ W,
                       const float* __restrict__ attn_l,
                       const float* __restrict__ attn_r,
                       double* __restrict__ Wlr_t,
                       int* __restrict__ cnt) {
    int k = threadIdx.x;  // 256 threads
    for (int j = 0; j < 8; ++j) {
        const float* attn = (j < 4) ? attn_l : attn_r;
        int hh = j & 3;
        double s = 0.0;
        for (int d = 0; d < DF; ++d)
            s += (double)W[k * NCOL + hh * DF + d] * (double)attn[hh * DF + d];
        Wlr_t[(size_t)j * IN_F + k] = s;
    }
    for (int i = k; i < N_DST; i += 256) cnt[i] = 0;
}

// ---------------- K1: scalar-W GEMM + el + histogram-with-rank -------------
// r22/r24's measured-best (137 us, eight variants probed): W via wave-uniform
// s_load into SGPRs (4 blocks/CU, 48% VALUBusy); r25's persistent W-in-LDS
// at 1 block/CU regressed to 215 (2 waves/SIMD can't hide LDS latency).
// unroll 1 (r23's unroll 2 regressed). el: half-split fp64 from LDS (lgkm
// only — r12/r17). h and el bit-identical across r11..r24.
__global__ __launch_bounds__(512) void k_gemm(const float* __restrict__ x,
                                              const float* __restrict__ W,
                                              const double* __restrict__ Wlr_t,
                                              const int* __restrict__ dst_idx,
                                              float* __restrict__ h,
                                              double* __restrict__ el,
                                              int* __restrict__ cnt,
                                              int* __restrict__ rank) {
    __shared__ float xs[64][68];    // 17.4 KB
    __shared__ double wlds[4][66];  // 2.1 KB
    const int tid = threadIdx.x;
    const int row0 = blockIdx.x * 64;
    const int lane = tid & 63;
    const int cg = __builtin_amdgcn_readfirstlane(tid >> 6);  // 0..7, SGPR
    const int c0 = cg * 16;
    const int srow = tid >> 3;        // score: row 0..63
    const int shh = tid & 3;          // score: head
    const int shalf = (tid >> 2) & 1; // score: k-half of each chunk

    const int r_a = tid >> 4;        // 0..31
    const int r_b = 32 + (tid >> 4); // 32..63
    const int q4 = (tid & 15) * 4;
    const int wj = tid >> 6, wk = tid & 63;  // wlds slot (tid<256 only)

    float4 acc0 = make_float4(0.f, 0.f, 0.f, 0.f);
    float4 acc1 = make_float4(0.f, 0.f, 0.f, 0.f);
    float4 acc2 = make_float4(0.f, 0.f, 0.f, 0.f);
    float4 acc3 = make_float4(0.f, 0.f, 0.f, 0.f);
    double sacc = 0.0;

    // prefetch chunk 0
    float4 pf0 = make_float4(0.f, 0.f, 0.f, 0.f);
    float4 pf1 = make_float4(0.f, 0.f, 0.f, 0.f);
    double pfw = 0.0;
    if (row0 + r_a < N_SRC)
        pf0 = *((const float4*)(x + (size_t)(row0 + r_a) * IN_F + q4));
    if (row0 + r_b < N_SRC)
        pf1 = *((const float4*)(x + (size_t)(row0 + r_b) * IN_F + q4));
    if (tid < 256)
        pfw = Wlr_t[(size_t)wj * IN_F + wk];

    for (int chunk = 0; chunk < 4; ++chunk) {
        const int kbase = chunk * 64;
        if (chunk) __syncthreads();
        *((float4*)&xs[r_a][q4]) = pf0;
        *((float4*)&xs[r_b][q4]) = pf1;
        if (tid < 256) wlds[wj][wk] = pfw;
        __syncthreads();

        if (chunk < 3) {
            const int nk = kbase + 64;
            if (row0 + r_a < N_SRC)
                pf0 = *((const float4*)(x + (size_t)(row0 + r_a) * IN_F + nk + q4));
            if (row0 + r_b < N_SRC)
                pf1 = *((const float4*)(x + (size_t)(row0 + r_b) * IN_F + nk + q4));
            if (tid < 256)
                pfw = Wlr_t[(size_t)wj * IN_F + nk + wk];
        }

        // ---- GEMM inner: W via wave-uniform (scalar) loads ----
#pragma unroll 1
        for (int kq = 0; kq < 64; kq += 4) {
            const float* wp = W + (size_t)(kbase + kq) * NCOL + c0;
            float4 r0a = *((const float4*)(wp + 0));
            float4 r0b = *((const float4*)(wp + 4));
            float4 r0c = *((const float4*)(wp + 8));
            float4 r0d = *((const float4*)(wp + 12));
            float4 r1a = *((const float4*)(wp + NCOL + 0));
            float4 r1b = *((const float4*)(wp + NCOL + 4));
            float4 r1c = *((const float4*)(wp + NCOL + 8));
            float4 r1d = *((const float4*)(wp + NCOL + 12));
            float4 r2a = *((const float4*)(wp + 2 * NCOL + 0));
            float4 r2b = *((const float4*)(wp + 2 * NCOL + 4));
            float4 r2c = *((const float4*)(wp + 2 * NCOL + 8));
            float4 r2d = *((const float4*)(wp + 2 * NCOL + 12));
            float4 r3a = *((const float4*)(wp + 3 * NCOL + 0));
            float4 r3b = *((const float4*)(wp + 3 * NCOL + 4));
            float4 r3c = *((const float4*)(wp + 3 * NCOL + 8));
            float4 r3d = *((const float4*)(wp + 3 * NCOL + 12));
            float4 xv = *((const float4*)&xs[lane][kq]);
            acc0.x += xv.x * r0a.x + xv.y * r1a.x + xv.z * r2a.x + xv.w * r3a.x;
            acc0.y += xv.x * r0a.y + xv.y * r1a.y + xv.z * r2a.y + xv.w * r3a.y;
            acc0.z += xv.x * r0a.z + xv.y * r1a.z + xv.z * r2a.z + xv.w * r3a.z;
            acc0.w += xv.x * r0a.w + xv.y * r1a.w + xv.z * r2a.w + xv.w * r3a.w;
            acc1.x += xv.x * r0b.x + xv.y * r1b.x + xv.z * r2b.x + xv.w * r3b.x;
            acc1.y += xv.x * r0b.y + xv.y * r1b.y + xv.z * r2b.y + xv.w * r3b.y;
            acc1.z += xv.x * r0b.z + xv.y * r1b.z + xv.z * r2b.z + xv.w * r3b.z;
            acc1.w += xv.x * r0b.w + xv.y * r1b.w + xv.z * r2b.w + xv.w * r3b.w;
            acc2.x += xv.x * r0c.x + xv.y * r1c.x + xv.z * r2c.x + xv.w * r3c.x;
            acc2.y += xv.x * r0c.y + xv.y * r1c.y + xv.z * r2c.y + xv.w * r3c.y;
            acc2.z += xv.x * r0c.z + xv.y * r1c.z + xv.z * r2c.z + xv.w * r3c.z;
            acc2.w += xv.x * r0c.w + xv.y * r1c.w + xv.z * r2c.w + xv.w * r3c.w;
            acc3.x += xv.x * r0d.x + xv.y * r1d.x + xv.z * r2d.x + xv.w * r3d.x;
            acc3.y += xv.x * r0d.y + xv.y * r1d.y + xv.z * r2d.y + xv.w * r3d.y;
            acc3.z += xv.x * r0d.z + xv.y * r1d.z + xv.z * r2d.z + xv.w * r3d.z;
            acc3.w += xv.x * r0d.w + xv.y * r1d.w + xv.z * r2d.w + xv.w * r3d.w;
        }

        // ---- score inner: half-dot (32 k) for el[srow][shh] ----
        {
            const int kb = shalf * 32;
#pragma unroll 4
            for (int k = 0; k < 32; k += 4) {
                float4 xv = *((const float4*)&xs[srow][kb + k]);
                double2 wa = *((const double2*)&wlds[shh][kb + k]);
                double2 wb = *((const double2*)&wlds[shh][kb + k + 2]);
                sacc += (double)xv.x * wa.x + (double)xv.y * wa.y
                      + (double)xv.z * wb.x + (double)xv.w * wb.y;
            }
        }
    }

    // write h: lane's row, 16 cols at c0
    {
        int row = row0 + lane;
        if (row < N_SRC) {
            float* hp = h + (size_t)row * NCOL + c0;
            *((float4*)(hp + 0)) = acc0;
            *((float4*)(hp + 4)) = acc1;
            *((float4*)(hp + 8)) = acc2;
            *((float4*)(hp + 12)) = acc3;
        }
    }

    // combine el halves (partner tid^4) and write
    sacc += __shfl_xor(sacc, 4);
    {
        int row = row0 + srow;
        if (shalf == 0 && row < N_SRC)
            el[(size_t)row * NH + shh] = sacc;
    }

    // histogram tail with rank capture (cnt zeroed by k_prep)
    for (int e = blockIdx.x * 512 + tid; e < NE; e += gridDim.x * 512)
        rank[e] = atomicAdd(cnt + dst_idx[e], 1);
}

// ---------------- k_scan: exclusive scan of cnt -> offsets ----------------
__global__ __launch_bounds__(1024) void k_scan(const int* __restrict__ cnt,
                                               int* __restrict__ offsets) {
    __shared__ int wsum[16];
    __shared__ int carry;
    int tid = threadIdx.x, lane = tid & 63, w = tid >> 6;
    if (tid == 0) carry = 0;
    __syncthreads();
    for (int base = 0; base < N_DST; base += 1024) {
        int i = base + tid;
        int v = (i < N_DST) ? cnt[i] : 0;
        int s = v;
#pragma unroll
        for (int off = 1; off < 64; off <<= 1) {
            int t = __shfl_up(s, off);
            if (lane >= off) s += t;
        }
        if (lane == 63) wsum[w] = s;
        __syncthreads();
        int wprefix = 0;
        for (int k = 0; k < w; ++k) wprefix += wsum[k];
        int incl = s + wprefix + carry;
        if (i < N_DST) offsets[i + 1] = incl;
        __syncthreads();
        if (tid == 1023) carry = incl;
        __syncthreads();
    }
    if (tid == 0) offsets[0] = 0;
}

// ---------------- k_fill: atomic-free scatter via precomputed rank --------
__global__ __launch_bounds__(256) void k_fill(const int* __restrict__ src_idx,
                                              const int* __restrict__ dst_idx,
                                              const int* __restrict__ offsets,
                                              const int* __restrict__ rank,
                                              int* __restrict__ edge_src) {
    int gid = blockIdx.x * 256 + threadIdx.x;
    if (gid >= NE) return;
    int d = dst_idx[gid];
    edge_src[offsets[d] + rank[gid]] = src_idx[gid];
}

// ---------------- K5: fused er + S + normalize + weighted gather ------------
__global__ __launch_bounds__(256) void k_fused(const int* __restrict__ offsets,
                                               const int* __restrict__ edge_src,
                                               const double* __restrict__ el,
                                               const float* __restrict__ x,
                                               const double* __restrict__ Wlr_t,
                                               const int* __restrict__ dst_to_src,
                                               const float* __restrict__ h,
                                               float* __restrict__ out) {
    __shared__ double att_sh[4][4][68];
    __shared__ int    s_sh[4][64];

    const int w = threadIdx.x >> 6;
    const int lane = threadIdx.x & 63;
    const int d = blockIdx.x * 4 + w;
    if (d >= N_DST) return;
    const int beg = offsets[d];
    const int deg = offsets[d + 1] - beg;

    // phase 0: er for this dst (exact fp64 from x)
    double er4[NH];
    {
        const int srcrow = dst_to_src[d];
        float4 xv = *((const float4*)(x + (size_t)srcrow * IN_F + lane * 4));
        const double xd[4] = {(double)xv.x, (double)xv.y, (double)xv.z, (double)xv.w};
#pragma unroll
        for (int hh = 0; hh < 4; ++hh) {
            const double* wp = Wlr_t + (size_t)(4 + hh) * IN_F + lane * 4;
            er4[hh] = xd[0] * wp[0] + xd[1] * wp[1] + xd[2] * wp[2] + xd[3] * wp[3];
        }
#pragma unroll
        for (int hh = 0; hh < 4; ++hh) {
#pragma unroll
            for (int m = 32; m >= 1; m >>= 1)
                er4[hh] += __shfl_xor(er4[hh], m);
        }
    }
    const double er0 = er4[0], er1 = er4[1], er2 = er4[2], er3 = er4[3];

    // phase 1: S[h] per-lane partials + butterfly; stash first-iter e/s
    double sum0 = 0.0, sum1 = 0.0, sum2 = 0.0, sum3 = 0.0;
    double e0r = 0.0, e1r = 0.0, e2r = 0.0, e3r = 0.0;
    int s_first = 0;
    for (int j = lane; j < deg; j += 64) {
        int s = edge_src[beg + j];
        double2 ela = *((const double2*)(el + (size_t)s * NH));
        double2 elb = *((const double2*)(el + (size_t)s * NH + 2));
        double e0 = ela.x + er0; e0 = (e0 >= 0.0) ? e0 : 0.2 * e0;
        double e1 = ela.y + er1; e1 = (e1 >= 0.0) ? e1 : 0.2 * e1;
        double e2 = elb.x + er2; e2 = (e2 >= 0.0) ? e2 : 0.2 * e2;
        double e3 = elb.y + er3; e3 = (e3 >= 0.0) ? e3 : 0.2 * e3;
        sum0 += e0; sum1 += e1; sum2 += e2; sum3 += e3;
        if (j == lane) { s_first = s; e0r = e0; e1r = e1; e2r = e2; e3r = e3; }
    }
#pragma unroll
    for (int m = 32; m >= 1; m >>= 1) {
        sum0 += __shfl_xor(sum0, m);
        sum1 += __shfl_xor(sum1, m);
        sum2 += __shfl_xor(sum2, m);
        sum3 += __shfl_xor(sum3, m);
    }

    if (lane < deg) {
        s_sh[w][lane] = s_first;
        att_sh[w][0][lane] = e0r / sum0;
        att_sh[w][1][lane] = e1r / sum1;
        att_sh[w][2][lane] = e2r / sum2;
        att_sh[w][3][lane] = e3r / sum3;
    }

    // phase 2: 2 edges in flight; lane = (js, col quad cq)
    const int js = lane >> 5;
    const int cq = lane & 31;
    const int hd = cq >> 3;
    const double Shd = (hd == 0) ? sum0 : (hd == 1) ? sum1 : (hd == 2) ? sum2 : sum3;
    const double erhd = (hd == 0) ? er0 : (hd == 1) ? er1 : (hd == 2) ? er2 : er3;

    double acc0 = 0.0, acc1 = 0.0, acc2 = 0.0, acc3 = 0.0;
    for (int j = js; j < deg; j += 2) {
        int s; double att;
        if (j < 64) {
            s = s_sh[w][j];
            att = att_sh[w][hd][j];
        } else {
            s = edge_src[beg + j];
            double e = el[(size_t)s * NH + hd] + erhd;
            e = (e >= 0.0) ? e : 0.2 * e;
            att = e / Shd;
        }
        float4 hv = *((const float4*)(h + (size_t)s * NCOL + cq * 4));
        acc0 += att * (double)hv.x;
        acc1 += att * (double)hv.y;
        acc2 += att * (double)hv.z;
        acc3 += att * (double)hv.w;
    }
    acc0 += __shfl_xor(acc0, 32);
    acc1 += __shfl_xor(acc1, 32);
    acc2 += __shfl_xor(acc2, 32);
    acc3 += __shfl_xor(acc3, 32);

    if (lane < 32) {
        *((float4*)(out + (size_t)d * NCOL + lane * 4)) =
            make_float4((float)acc0, (float)acc1, (float)acc2, (float)acc3);
    }
}

extern "C" void kernel_launch(void* const* d_in, const int* in_sizes, int n_in,
                              void* d_out, int out_size, void* d_ws, size_t ws_size,
                              hipStream_t stream) {
    const float* x      = (const float*)d_in[0];
    const float* W      = (const float*)d_in[1];
    const float* attn_l = (const float*)d_in[2];
    const float* attn_r = (const float*)d_in[3];
    const int* src_idx  = (const int*)d_in[4];
    const int* dst_idx  = (const int*)d_in[5];
    const int* dst_to_src = (const int*)d_in[6];
    float* out = (float*)d_out;

    char* p = (char*)d_ws;
    double* Wlr_t  = (double*)p;  p += (size_t)8 * IN_F * sizeof(double);     // 16 KB
    double* el     = (double*)p;  p += (size_t)N_SRC * NH * sizeof(double);   // 3.2 MB
    float*  h      = (float*)p;   p += (size_t)N_SRC * NCOL * sizeof(float);  // 51.2 MB
    int*    cnt      = (int*)p;   p += (size_t)N_DST * sizeof(int);
    int*    offsets  = (int*)p;   p += (size_t)(N_DST + 1) * sizeof(int);
    int*    rank     = (int*)p;   p += (size_t)NE * sizeof(int);
    int*    edge_src = (int*)p;   p += (size_t)NE * sizeof(int);

    k_prep<<<1, 256, 0, stream>>>(W, attn_l, attn_r, Wlr_t, cnt);
    k_gemm<<<(N_SRC + 63) / 64, 512, 0, stream>>>(x, W, Wlr_t, dst_idx, h, el, cnt, rank);
    k_scan<<<1, 1024, 0, stream>>>(cnt, offsets);
    k_fill<<<(NE + 255) / 256, 256, 0, stream>>>(src_idx, dst_idx, offsets, rank, edge_src);
    k_fused<<<N_DST / 4, 256, 0, stream>>>(offsets, edge_src, el, x, Wlr_t, dst_to_src, h, out);
}